// Round 7
// baseline (80.392 us; speedup 1.0000x reference)
//
#include <hip/hip_runtime.h>
#include <hip/hip_bf16.h>

#define HM_W 512
#define HM_H 512
#define PW   508   // 512 - 5 + 1

__device__ __forceinline__ void load_row8(const float* __restrict__ hm, int y, int c0, float v[8]) {
    const float4* rp = reinterpret_cast<const float4*>(hm + y * HM_W + c0);
    float4 a = rp[0];
    float4 b = rp[1];
    v[0]=a.x; v[1]=a.y; v[2]=a.z; v[3]=a.w;
    v[4]=b.x; v[5]=b.y; v[6]=b.z; v[7]=b.w;
}

// Per-lane 5-wide window sums from per-lane colsums s[0..7] (cols lane*8..lane*8+7),
// cross-lane tail via shfl, then wave-wide argmax (tie-break: lowest column).
// Whole wave must be active. All lanes end with the result.
__device__ __forceinline__ void row_best_shfl(const float s[8], int lane, float& bv, int& bc) {
    float cb[12];
#pragma unroll
    for (int j = 0; j < 8; ++j) cb[j] = s[j];
#pragma unroll
    for (int j = 0; j < 4; ++j) cb[8 + j] = __shfl_down(s[j], 1);
    bv = -__builtin_inff();
    bc = 0x7fffffff;
    int c0 = lane * 8;
#pragma unroll
    for (int j = 0; j < 8; ++j) {
        int c = c0 + j;
        float w = cb[j] + cb[j + 1] + cb[j + 2] + cb[j + 3] + cb[j + 4];
        if (c < PW && w > bv) { bv = w; bc = c; }   // ascending c keeps lowest col on tie
    }
#pragma unroll
    for (int m = 1; m < 64; m <<= 1) {
        float ov = __shfl_xor(bv, m);
        int   oc = __shfl_xor(bc, m);
        if (ov > bv || (ov == bv && oc < bc)) { bv = ov; bc = oc; }
    }
}

// Phase 1 (round-2 exact, best known): rolling 5-row register window,
// 16 aggregate rows per wave from 20 row-loads. grid = (8,128), block = 256.
__global__ void phase1_kernel(const float* __restrict__ hm_all,
                              float* __restrict__ rowv_ws, int* __restrict__ rowc_ws) {
    int b = blockIdx.y;
    int wave = threadIdx.x >> 6;
    int lane = threadIdx.x & 63;
    int c0 = lane * 8;
    const float* hm = hm_all + (size_t)b * HM_W * HM_H;

    int rbase = (blockIdx.x * 4 + wave) * 16;
    if (rbase >= PW) return;

    float w0[8], w1[8], w2[8], w3[8], w4[8];
    load_row8(hm, rbase + 0, c0, w0);
    load_row8(hm, rbase + 1, c0, w1);
    load_row8(hm, rbase + 2, c0, w2);
    load_row8(hm, rbase + 3, c0, w3);

#pragma unroll
    for (int rr = 0; rr < 16; ++rr) {
        int y = rbase + rr;
        if (y >= PW) break;                 // wave-uniform
        load_row8(hm, y + 4, c0, w4);
        float s[8];
#pragma unroll
        for (int j = 0; j < 8; ++j)
            s[j] = ((((w0[j] + w1[j]) + w2[j]) + w3[j]) + w4[j]);
        float bv; int bc;
        row_best_shfl(s, lane, bv, bc);
        if (lane == 0) {
            rowv_ws[b * 512 + y] = bv;
            rowc_ws[b * 512 + y] = bc;
        }
#pragma unroll
        for (int j = 0; j < 8; ++j) { w0[j] = w1[j]; w1[j] = w2[j]; w2[j] = w3[j]; w3[j] = w4[j]; }
    }
}

// Phase 2: speculative double-peak extraction. Data is non-negative (uniform[0,1)),
// so repairs only DECREASE row maxima. After peak1 at row r1, if the best row-max
// strictly outside rows [r1-4, r1+4] exceeds the pre-repair max inside that zone
// (strict >), the 2nd argmax is provably outside the zone => commit both peaks in
// one pass. Require |r2-r1| > 8 so the two repair row-sets are disjoint (then
// peak2's 5x5 mask rows [r2, r2+4] can't touch zone1 rows either). Fallback =
// exact single-peak path. ONE barrier per pass; repairs go to a double-buffered
// side list, applied as overrides next pass while rowv is patched in place
// (race-benign: patch writes equal the override values readers would use).
// grid = 128, block = 640 (10 waves; list item li handled by wave li%10).
__global__ void __launch_bounds__(640) phase2_kernel(const float* __restrict__ hm_all,
                              const float* __restrict__ rowv_ws,
                              const int* __restrict__ rowc_ws,
                              int* __restrict__ out) {
    int b = blockIdx.x;
    const float* hm = hm_all + (size_t)b * HM_W * HM_H;
    int t = threadIdx.x;
    int wave = t >> 6, lane = t & 63;
    int c0 = lane * 8;

    __shared__ float rowv[512];
    __shared__ int   rowc[512];
    __shared__ float updv[2][18];
    __shared__ int   updc[2][18];

    if (t < 512) {
        if (t < PW) { rowv[t] = rowv_ws[b * 512 + t]; rowc[t] = rowc_ws[b * 512 + t]; }
        else        { rowv[t] = -__builtin_inff();    rowc[t] = 0; }
    }

    int zrr[6], zcc[6];
    int py0a = -1000, pna = 0, py0b = -1000, pnb = 0;  // prev-pass repair ranges
    int cbuf = 0;
    int npk = 0;

    while (npk < 6) {
        __syncthreads();   // the ONLY barrier: prev repair writes -> this pass's reads
        int pbuf = cbuf ^ 1;

        // ---- scan1: argmax over table w/ overrides (tie-break lowest row) ----
        float bv1 = -__builtin_inff(); int bi1 = 0x7fffffff;
#pragma unroll
        for (int j = 0; j < 8; ++j) {
            int idx = j * 64 + lane;
            float v = rowv[idx];
            unsigned ua = (unsigned)(idx - py0a);
            if (ua < (unsigned)pna) v = updv[pbuf][ua];
            unsigned ub = (unsigned)(idx - py0b);
            if (ub < (unsigned)pnb) v = updv[pbuf][pna + ub];
            if (v > bv1) { bv1 = v; bi1 = idx; }   // ascending idx: lowest row on tie
        }
#pragma unroll
        for (int m = 1; m < 64; m <<= 1) {
            float ov = __shfl_xor(bv1, m);
            int   oi = __shfl_xor(bi1, m);
            if (ov > bv1 || (ov == bv1 && oi < bi1)) { bv1 = ov; bi1 = oi; }
        }
        int fr1 = bi1;
        int fc1 = rowc[fr1];
        {
            unsigned ua = (unsigned)(fr1 - py0a);
            if (ua < (unsigned)pna) fc1 = updc[pbuf][ua];
            unsigned ub = (unsigned)(fr1 - py0b);
            if (ub < (unsigned)pnb) fc1 = updc[pbuf][pna + ub];
        }
#pragma unroll
        for (int k = 0; k < 6; ++k) if (k == npk) { zrr[k] = fr1; zcc[k] = fc1; }
        if (t == 0) {
            out[b * 12 + npk * 2 + 0] = fc1 + 2;   // SWAP_RC: (c+R, r+R)
            out[b * 12 + npk * 2 + 1] = fr1 + 2;
        }

        // ---- patch rowv/rowc with previous pass's repairs (race-benign) ----
        if (t < 18) {
            if (t < pna) {
                rowv[py0a + t] = updv[pbuf][t]; rowc[py0a + t] = updc[pbuf][t];
            } else if (t - pna < pnb) {
                int yy = py0b + (t - pna);
                rowv[yy] = updv[pbuf][t]; rowc[yy] = updc[pbuf][t];
            }
        }

        // ---- zone bounds for peak1 ----
        int zlo = fr1 - 4 < 0 ? 0 : fr1 - 4;
        int zhi = fr1 + 4 > PW - 1 ? PW - 1 : fr1 + 4;
        int zn  = zhi - zlo + 1;

        // ---- V_zone: pre-repair max inside the zone (uniform-addr LDS broadcast) ----
        float Vz = -__builtin_inff();
#pragma unroll
        for (int k = 0; k < 9; ++k) {
            if (k < zn) {
                int yy = zlo + k;
                float v = rowv[yy];
                unsigned ua = (unsigned)(yy - py0a);
                if (ua < (unsigned)pna) v = updv[pbuf][ua];
                unsigned ub = (unsigned)(yy - py0b);
                if (ub < (unsigned)pnb) v = updv[pbuf][pna + ub];
                Vz = v > Vz ? v : Vz;
            }
        }

        // ---- scan2: argmax excluding zone rows ----
        float bv2 = -__builtin_inff(); int bi2 = 0x7fffffff;
#pragma unroll
        for (int j = 0; j < 8; ++j) {
            int idx = j * 64 + lane;
            float v = rowv[idx];
            unsigned ua = (unsigned)(idx - py0a);
            if (ua < (unsigned)pna) v = updv[pbuf][ua];
            unsigned ub = (unsigned)(idx - py0b);
            if (ub < (unsigned)pnb) v = updv[pbuf][pna + ub];
            if ((unsigned)(idx - zlo) < (unsigned)zn) v = -__builtin_inff();
            if (v > bv2) { bv2 = v; bi2 = idx; }
        }
#pragma unroll
        for (int m = 1; m < 64; m <<= 1) {
            float ov = __shfl_xor(bv2, m);
            int   oi = __shfl_xor(bi2, m);
            if (ov > bv2 || (ov == bv2 && oi < bi2)) { bv2 = ov; bi2 = oi; }
        }
        int fr2 = bi2;
        bool acc = (npk < 5) && (bv2 > Vz) && (fr2 > fr1 + 8 || fr2 < fr1 - 8);
        if (acc) {
            int fc2 = rowc[fr2];
            unsigned ua = (unsigned)(fr2 - py0a);
            if (ua < (unsigned)pna) fc2 = updc[pbuf][ua];
            unsigned ub = (unsigned)(fr2 - py0b);
            if (ub < (unsigned)pnb) fc2 = updc[pbuf][pna + ub];
#pragma unroll
            for (int k = 0; k < 6; ++k) if (k == npk + 1) { zrr[k] = fr2; zcc[k] = fc2; }
            if (t == 0) {
                out[b * 12 + (npk + 1) * 2 + 0] = fc2 + 2;
                out[b * 12 + (npk + 1) * 2 + 1] = fr2 + 2;
            }
        }
        int newn = npk + (acc ? 2 : 1);
        if (newn >= 6) break;

        // ---- repair rows: zone1 [zlo, zhi] (+ zone2 if accepted), list-parallel ----
        int y0b = fr2 - 4 < 0 ? 0 : fr2 - 4;
        int y1b = fr2 + 4 > PW - 1 ? PW - 1 : fr2 + 4;
        int na = zn;
        int nb = acc ? (y1b - y0b + 1) : 0;
#pragma unroll
        for (int p = 0; p < 2; ++p) {
            int li = wave + p * 10;        // wave-uniform
            if (li < na + nb) {
                int y = (li < na) ? (zlo + li) : (y0b + (li - na));
                float s[8];
#pragma unroll
                for (int j = 0; j < 8; ++j) s[j] = 0.f;
#pragma unroll
                for (int i = 0; i < 5; ++i) {
                    float v[8];
                    load_row8(hm, y + i, c0, v);
#pragma unroll
                    for (int j = 0; j < 8; ++j) {
                        float vv = v[j];
#pragma unroll
                        for (int k = 0; k < 6; ++k) {
                            if (k < newn && (unsigned)(y + i - zrr[k]) < 5u
                                         && (unsigned)(c0 + j - zcc[k]) < 5u)
                                vv = 0.f;
                        }
                        s[j] += vv;
                    }
                }
                float nv; int nc;
                row_best_shfl(s, lane, nv, nc);
                if (lane == 0) { updv[cbuf][li] = nv; updc[cbuf][li] = nc; }
            }
        }

        py0a = zlo; pna = na; py0b = y0b; pnb = nb;
        cbuf ^= 1;
        npk = newn;
    }
}

extern "C" void kernel_launch(void* const* d_in, const int* in_sizes, int n_in,
                              void* d_out, int out_size, void* d_ws, size_t ws_size,
                              hipStream_t stream) {
    const float* hm = (const float*)d_in[0];
    int* out = (int*)d_out;
    float* rowv_ws = (float*)d_ws;
    int*   rowc_ws = (int*)((char*)d_ws + (size_t)128 * 512 * sizeof(float));

    phase1_kernel<<<dim3(8, 128), dim3(256), 0, stream>>>(hm, rowv_ws, rowc_ws);
    phase2_kernel<<<dim3(128), dim3(640), 0, stream>>>(hm, rowv_ws, rowc_ws, out);
}

// Round 8
// 52.960 us; speedup vs baseline: 1.5180x; 1.5180x over previous
//
#include <hip/hip_runtime.h>
#include <hip/hip_bf16.h>

#define HM_W 512
#define HM_H 512
#define PW   508   // 512 - 5 + 1

__device__ __forceinline__ void load_row8(const float* __restrict__ hm, int y, int c0, float v[8]) {
    const float4* rp = reinterpret_cast<const float4*>(hm + y * HM_W + c0);
    float4 a = rp[0];
    float4 b = rp[1];
    v[0]=a.x; v[1]=a.y; v[2]=a.z; v[3]=a.w;
    v[4]=b.x; v[5]=b.y; v[6]=b.z; v[7]=b.w;
}

// Per-lane 5-wide window sums from per-lane colsums s[0..7] (cols lane*8..lane*8+7),
// cross-lane tail via shfl, then wave-wide argmax (tie-break: lowest column).
// Whole wave must be active. All lanes end with the result.
__device__ __forceinline__ void row_best_shfl(const float s[8], int lane, float& bv, int& bc) {
    float cb[12];
#pragma unroll
    for (int j = 0; j < 8; ++j) cb[j] = s[j];
#pragma unroll
    for (int j = 0; j < 4; ++j) cb[8 + j] = __shfl_down(s[j], 1);
    bv = -__builtin_inff();
    bc = 0x7fffffff;
    int c0 = lane * 8;
#pragma unroll
    for (int j = 0; j < 8; ++j) {
        int c = c0 + j;
        float w = cb[j] + cb[j + 1] + cb[j + 2] + cb[j + 3] + cb[j + 4];
        if (c < PW && w > bv) { bv = w; bc = c; }   // ascending c keeps lowest col on tie
    }
#pragma unroll
    for (int m = 1; m < 64; m <<= 1) {
        float ov = __shfl_xor(bv, m);
        int   oc = __shfl_xor(bc, m);
        if (ov > bv || (ov == bv && oc < bc)) { bv = ov; bc = oc; }
    }
}

// Phase 1: rolling 5-row register window, 16 output rows per wave, with the 4
// wave-boundary overlap rows shared through LDS: wave w's iterations 12..15 read
// rows rbase+16..19 from lds[w] (written by wave w+1 from its own first-4 loads;
// wave 3 loads its 4 tail rows into lds[3] itself). Per block: 68 row-loads per
// 64 output rows = 1.0625x redundancy (was 1.25x). Values are bit-identical to
// the global loads, so all sum chains are unchanged.
// grid = (8,128) = 1024 blocks (4 blocks/CU), block = 256 (4 waves). LDS 32 KB.
__global__ void phase1_kernel(const float* __restrict__ hm_all,
                              float* __restrict__ rowv_ws, int* __restrict__ rowc_ws) {
    int b = blockIdx.y;
    int wave = threadIdx.x >> 6;
    int lane = threadIdx.x & 63;
    int c0 = lane * 8;
    const float* hm = hm_all + (size_t)b * HM_W * HM_H;

    __shared__ float lds[4][4][512];

    // strips 0..31 cover rows 0..511; rbase max = 496 < PW, so no wave exits early.
    int rbase = (blockIdx.x * 4 + wave) * 16;

    float w0[8], w1[8], w2[8], w3[8], w4[8];
    load_row8(hm, rbase + 0, c0, w0);
    load_row8(hm, rbase + 1, c0, w1);
    load_row8(hm, rbase + 2, c0, w2);
    load_row8(hm, rbase + 3, c0, w3);

    // Share first-4 rows with the previous wave.
    if (wave >= 1) {
        float* dst = &lds[wave - 1][0][0];
#pragma unroll
        for (int j = 0; j < 8; ++j) dst[0 * 512 + c0 + j] = w0[j];
#pragma unroll
        for (int j = 0; j < 8; ++j) dst[1 * 512 + c0 + j] = w1[j];
#pragma unroll
        for (int j = 0; j < 8; ++j) dst[2 * 512 + c0 + j] = w2[j];
#pragma unroll
        for (int j = 0; j < 8; ++j) dst[3 * 512 + c0 + j] = w3[j];
    }
    if (wave == 3) {
        // Tail rows rbase+16..19 (clamped; clamped ones are only consumed by
        // iterations with y >= PW, which never execute).
#pragma unroll
        for (int k = 0; k < 4; ++k) {
            int ty = rbase + 16 + k; ty = ty > (HM_H - 1) ? (HM_H - 1) : ty;
            float tv[8];
            load_row8(hm, ty, c0, tv);
#pragma unroll
            for (int j = 0; j < 8; ++j) lds[3][k][c0 + j] = tv[j];
        }
    }
    __syncthreads();

#pragma unroll
    for (int rr = 0; rr < 16; ++rr) {
        int y = rbase + rr;
        if (y >= PW) break;                 // wave-uniform
        if (rr < 12) {
            load_row8(hm, y + 4, c0, w4);   // own rows rbase+4..15
        } else {
            const float* src = &lds[wave][rr - 12][c0];
            const float4* sp = reinterpret_cast<const float4*>(src);
            float4 a = sp[0], bb = sp[1];
            w4[0]=a.x; w4[1]=a.y; w4[2]=a.z; w4[3]=a.w;
            w4[4]=bb.x; w4[5]=bb.y; w4[6]=bb.z; w4[7]=bb.w;
        }
        float s[8];
#pragma unroll
        for (int j = 0; j < 8; ++j)
            s[j] = ((((w0[j] + w1[j]) + w2[j]) + w3[j]) + w4[j]);
        float bv; int bc;
        row_best_shfl(s, lane, bv, bc);
        if (lane == 0) {
            rowv_ws[b * 512 + y] = bv;
            rowc_ws[b * 512 + y] = bc;
        }
#pragma unroll
        for (int j = 0; j < 8; ++j) { w0[j] = w1[j]; w1[j] = w2[j]; w2[j] = w3[j]; w3[j] = w4[j]; }
    }
}

// Phase 2 (round-6 exact, best known): LDS row table + ONE barrier per iteration.
// Repairs write a tiny double-buffered side buffer; next iteration's argmax
// overrides stale rowv entries from it while 9 threads patch rowv in place
// (race-benign: readers discard any racy read via the override; writes carry the
// identical value). grid = 128, block = 640 (10 waves; waves 0..8 repair rows).
__global__ void __launch_bounds__(640) phase2_kernel(const float* __restrict__ hm_all,
                              const float* __restrict__ rowv_ws,
                              const int* __restrict__ rowc_ws,
                              int* __restrict__ out) {
    int b = blockIdx.x;
    const float* hm = hm_all + (size_t)b * HM_W * HM_H;
    int t = threadIdx.x;
    int wave = t >> 6, lane = t & 63;
    int c0 = lane * 8;

    __shared__ float rowv[512];
    __shared__ int   rowc[512];
    __shared__ float updv[2][9];
    __shared__ int   updc[2][9];
    __shared__ int   upd_y0[2];
    __shared__ int   upd_n[2];

    if (t < 512) {
        if (t < PW) { rowv[t] = rowv_ws[b * 512 + t]; rowc[t] = rowc_ws[b * 512 + t]; }
        else        { rowv[t] = -__builtin_inff();    rowc[t] = 0; }
    }
    if (t == 0) { upd_y0[1] = -1000; upd_n[1] = 0; }   // it=0 reads pbuf=1: empty

    int zrr[6], zcc[6];

#pragma unroll
    for (int it = 0; it < 6; ++it) {
        __syncthreads();   // the ONLY barrier: prev repair writes -> this iter's reads

        int pbuf = (it + 1) & 1;           // buffer written by previous iteration
        int py0 = upd_y0[pbuf];            // block-uniform
        int pn  = upd_n[pbuf];

        // ---- per-thread argmax over 8 stride-64 entries, overriding stale rows ----
        float bv = -__builtin_inff(); int bi = 0x7fffffff;
#pragma unroll
        for (int j = 0; j < 8; ++j) {
            int idx = j * 64 + lane;
            float v = rowv[idx];
            unsigned u = (unsigned)(idx - py0);
            if (u < (unsigned)pn) v = updv[pbuf][u];
            if (v > bv) { bv = v; bi = idx; }   // ascending idx keeps lowest row on tie
        }
#pragma unroll
        for (int m = 1; m < 64; m <<= 1) {
            float ov = __shfl_xor(bv, m);
            int   oi = __shfl_xor(bi, m);
            if (ov > bv || (ov == bv && oi < bi)) { bv = ov; bi = oi; }
        }
        int fr = bi;
        unsigned uf = (unsigned)(fr - py0);
        int fc = (uf < (unsigned)pn) ? updc[pbuf][uf] : rowc[fr];   // LDS broadcast
        zrr[it] = fr; zcc[it] = fc;
        if (t == 0) {
            out[b * 12 + it * 2 + 0] = fc + 2;   // SWAP_RC: (c+R, r+R)
            out[b * 12 + it * 2 + 1] = fr + 2;
        }

        // ---- patch rowv/rowc with the previous iteration's repairs ----
        // Concurrent with the reads above, but race-benign (see header comment).
        if (t < 9 && t < pn) {
            int yy = py0 + t;
            rowv[yy] = updv[pbuf][t];
            rowc[yy] = updc[pbuf][t];
        }

        if (it == 5) break;                // compile-time: last peak needs no repair

        // ---- repair the <=9 affected rows, one wave each; loads issue now ----
        int y0 = fr - 4 < 0 ? 0 : fr - 4;
        int y1 = fr + 4 > PW - 1 ? PW - 1 : fr + 4;
        int buf = it & 1;
        int y = y0 + wave;                 // wave-uniform predicate
        if (wave < 9 && y <= y1) {
            float s[8];
#pragma unroll
            for (int j = 0; j < 8; ++j) s[j] = 0.f;
#pragma unroll
            for (int i = 0; i < 5; ++i) {
                float v[8];
                load_row8(hm, y + i, c0, v);
#pragma unroll
                for (int j = 0; j < 8; ++j) {
                    float vv = v[j];
#pragma unroll
                    for (int k = 0; k < 6; ++k) {
                        if (k <= it && (unsigned)(y + i - zrr[k]) < 5u
                                    && (unsigned)(c0 + j - zcc[k]) < 5u)
                            vv = 0.f;
                    }
                    s[j] += vv;
                }
            }
            float nv; int nc;
            row_best_shfl(s, lane, nv, nc);
            if (lane == 0) { updv[buf][wave] = nv; updc[buf][wave] = nc; }
        }
        if (t == 0) { upd_y0[buf] = y0; upd_n[buf] = y1 - y0 + 1; }
    }
}

extern "C" void kernel_launch(void* const* d_in, const int* in_sizes, int n_in,
                              void* d_out, int out_size, void* d_ws, size_t ws_size,
                              hipStream_t stream) {
    const float* hm = (const float*)d_in[0];
    int* out = (int*)d_out;
    float* rowv_ws = (float*)d_ws;
    int*   rowc_ws = (int*)((char*)d_ws + (size_t)128 * 512 * sizeof(float));

    phase1_kernel<<<dim3(8, 128), dim3(256), 0, stream>>>(hm, rowv_ws, rowc_ws);
    phase2_kernel<<<dim3(128), dim3(640), 0, stream>>>(hm, rowv_ws, rowc_ws, out);
}